// Round 12
// baseline (31.630 us; speedup 1.0000x reference)
//
#include <hip/hip_runtime.h>

// log sigma_{63,64} of exp(x) along classes: x (2048,10000) f32 -> out (2,2048) f32.
// 256 threads/sample. Global exponential tilt tau; 256 register leaves (deg<=6),
// RL1/RL2 shuffle merges (deg 7, 11) -> L3..L7 float4-TILED convs in LDS
// (static trips, 4 outputs/lane, ds_read_b128) -> L8 final degrees 63,64.
// Per-merge max-normalization (scLog write-once). 2 barriers; L3..L6 wave-local.
// (Round 12 = round 10 resubmitted again; rounds 10/11 benches died on infra.)

#define NS 2048
#define NC 10000
#define KSEL 64

// LDS arena float offsets/strides: row = [lowpad z | coeffs | top z]
#define OW2 0      // 64 rows x 32  : [12z | 12 (deg<=11) | 8z]
#define OW3 2048   // 32 rows x 44  : [20z | 17 (deg<=16) | 7z]
#define OW4 3456   // 16 rows x 60  : [24z | 21 (deg<=20) | 15z]
#define OW5 4416   //  8 rows x 84  : [36z | 33 (deg<=32) | 15z]
#define OW6 5088   //  4 rows x 116 : [48z | 45 (deg<=44) | 23z]
#define OW7 5552   //  2 rows x 68  : [65 (deg<=64) | 3z]
#define LDSF 5688  // total floats (= 1422 float4)

__device__ __forceinline__ float4 ld4(const float* p) { return *(const float4*)p; }
__device__ __forceinline__ void st4(float* p, float a, float b, float c, float d) {
  *(float4*)p = make_float4(a, b, c, d);
}

// 16-FMA sliding block: acc_q += a4[k] * b_{j0+q-(i0+k)} with bh=B[j0-i0..+3], bl=B[j0-i0-4..-1]
#define CONV4(a4, bl, bh)                                                               \
  a0 = fmaf(a4.x, bh.x, a0); a1 = fmaf(a4.x, bh.y, a1); a2 = fmaf(a4.x, bh.z, a2); a3 = fmaf(a4.x, bh.w, a3); \
  a0 = fmaf(a4.y, bl.w, a0); a1 = fmaf(a4.y, bh.x, a1); a2 = fmaf(a4.y, bh.y, a2); a3 = fmaf(a4.y, bh.z, a3); \
  a0 = fmaf(a4.z, bl.z, a0); a1 = fmaf(a4.z, bl.w, a1); a2 = fmaf(a4.z, bh.x, a2); a3 = fmaf(a4.z, bh.y, a3); \
  a0 = fmaf(a4.w, bl.y, a0); a1 = fmaf(a4.w, bl.z, a1); a2 = fmaf(a4.w, bl.w, a2); a3 = fmaf(a4.w, bh.x, a3)

__global__ __launch_bounds__(256, 4)
void logesp_kernel(const float* __restrict__ x, float* __restrict__ out) {
  __shared__ float LW[LDSF];
  __shared__ float scLog[64];   // L3:0..31 L4:32..47 L5:48..55 L6:56..59 L7:60..61
  __shared__ float red[8];      // [0..3] per-wave sum(w); [4..7] per-wave sum(S)

  const int t  = threadIdx.x;
  const int wv = t >> 6;
  const int s  = blockIdx.x;

  // ---------- zero the whole LDS arena (pads stay zero forever) ----------
  {
    float4* z4 = (float4*)LW;
#pragma unroll
    for (int u = 0; u < 6; ++u) {
      const int idx = t + u * 256;
      if (idx < LDSF / 4) z4[idx] = make_float4(0.f, 0.f, 0.f, 0.f);
    }
  }

  // ---------- phase 1: leaf ESP deg<=6, all 10 loads batched up front ----------
  const float4* xv = (const float4*)(x + (size_t)s * NC);   // 2500 float4
  float4 buf[10];
#pragma unroll
  for (int it = 0; it < 9; ++it) buf[it] = xv[t + it * 256];  // 2304 chunks
  buf[9] = make_float4(-1e30f, -1e30f, -1e30f, -1e30f);       // exp -> 0
  if (t < 196) buf[9] = xv[2304 + t];                          // 2304..2499

  float c0 = 1.f, c1 = 0.f, c2 = 0.f, c3 = 0.f, c4 = 0.f, c5 = 0.f, c6 = 0.f;
  float sw = 0.f;
#pragma unroll
  for (int it = 0; it < 10; ++it) {
    const float4 v = buf[it];
#pragma unroll
    for (int q = 0; q < 4; ++q) {
      const float xval = q == 0 ? v.x : q == 1 ? v.y : q == 2 ? v.z : v.w;
      const float w = __expf(xval);
      sw += w;
      c6 = fmaf(w, c5, c6);
      c5 = fmaf(w, c4, c5);
      c4 = fmaf(w, c3, c4);
      c3 = fmaf(w, c2, c3);
      c2 = fmaf(w, c1, c2);
      c1 = fmaf(w, c0, c1);
    }
  }

  // ---------- tilt tau = ln(wbar*(NC-K)/K) ----------
#pragma unroll
  for (int m = 1; m < 64; m <<= 1) sw += __shfl_xor(sw, m);
  if ((t & 63) == 0) red[wv] = sw;
  __syncthreads();                                   // barrier 1 (also covers zeroing)
  const float wsum = red[0] + red[1] + red[2] + red[3];
  const float tau = __logf(wsum * ((float)(NC - KSEL) / ((float)KSEL * (float)NC)));

  // tilt + leaf max-normalize (registers)
  {
    const float f1 = __expf(-tau);
    const float f2 = f1 * f1, f3 = f2 * f1, f4v = f2 * f2, f5 = f4v * f1, f6 = f4v * f2;
    c1 *= f1; c2 *= f2; c3 *= f3; c4 *= f4v; c5 *= f5; c6 *= f6;
  }
  {
    const float mx = fmaxf(fmaxf(fmaxf(c0, c1), fmaxf(c2, c3)), fmaxf(fmaxf(c4, c5), c6));
    const float invm = 1.f / mx;
    c0 *= invm; c1 *= invm; c2 *= invm; c3 *= invm; c4 *= invm; c5 *= invm; c6 *= invm;
    float Sr = __logf(mx);
#pragma unroll
    for (int m = 1; m < 64; m <<= 1) Sr += __shfl_xor(Sr, m);
    if ((t & 63) == 0) red[4 + wv] = Sr;
  }

  // ---------- RL1: pair merge via shfl (deg 7) ----------
  const float q0 = __shfl_xor(c0, 1), q1 = __shfl_xor(c1, 1), q2 = __shfl_xor(c2, 1),
              q3 = __shfl_xor(c3, 1), q4 = __shfl_xor(c4, 1), q5 = __shfl_xor(c5, 1),
              q6 = __shfl_xor(c6, 1);
  const float e0 = c0 * q0;
  const float e1 = fmaf(c1, q0, c0 * q1);
  const float e2 = fmaf(c2, q0, fmaf(c1, q1, c0 * q2));
  const float e3 = fmaf(c3, q0, fmaf(c2, q1, fmaf(c1, q2, c0 * q3)));
  const float e4 = fmaf(c4, q0, fmaf(c3, q1, fmaf(c2, q2, fmaf(c1, q3, c0 * q4))));
  const float e5 = fmaf(c5, q0, fmaf(c4, q1, fmaf(c3, q2, fmaf(c2, q3, fmaf(c1, q4, c0 * q5)))));
  const float e6 = fmaf(c6, q0, fmaf(c5, q1, fmaf(c4, q2, fmaf(c3, q3, fmaf(c2, q4, fmaf(c1, q5, c0 * q6))))));
  const float e7 = fmaf(c6, q1, fmaf(c5, q2, fmaf(c4, q3, fmaf(c3, q4, fmaf(c2, q5, c1 * q6)))));

  // ---------- RL2: 4-leaf merge via shfl (deg 11) ----------
  const float f0 = __shfl_xor(e0, 2), f1 = __shfl_xor(e1, 2), f2 = __shfl_xor(e2, 2),
              f3 = __shfl_xor(e3, 2), f4 = __shfl_xor(e4, 2), f5 = __shfl_xor(e5, 2),
              f6 = __shfl_xor(e6, 2), f7 = __shfl_xor(e7, 2);
  const float g0 = e0 * f0;
  const float g1 = fmaf(e1, f0, e0 * f1);
  const float g2 = fmaf(e2, f0, fmaf(e1, f1, e0 * f2));
  const float g3 = fmaf(e3, f0, fmaf(e2, f1, fmaf(e1, f2, e0 * f3)));
  const float g4 = fmaf(e4, f0, fmaf(e3, f1, fmaf(e2, f2, fmaf(e1, f3, e0 * f4))));
  const float g5 = fmaf(e5, f0, fmaf(e4, f1, fmaf(e3, f2, fmaf(e2, f3, fmaf(e1, f4, e0 * f5)))));
  const float g6 = fmaf(e6, f0, fmaf(e5, f1, fmaf(e4, f2, fmaf(e3, f3, fmaf(e2, f4, fmaf(e1, f5, e0 * f6))))));
  const float g7 = fmaf(e7, f0, fmaf(e6, f1, fmaf(e5, f2, fmaf(e4, f3, fmaf(e3, f4, fmaf(e2, f5, fmaf(e1, f6, e0 * f7)))))));
  const float g8 = fmaf(e7, f1, fmaf(e6, f2, fmaf(e5, f3, fmaf(e4, f4, fmaf(e3, f5, fmaf(e2, f6, e1 * f7))))));
  const float g9 = fmaf(e7, f2, fmaf(e6, f3, fmaf(e5, f4, fmaf(e4, f5, fmaf(e3, f6, e2 * f7)))));
  const float g10 = fmaf(e7, f3, fmaf(e6, f4, fmaf(e5, f5, fmaf(e4, f6, e3 * f7))));
  const float g11 = fmaf(e7, f4, fmaf(e6, f5, fmaf(e5, f6, e4 * f7)));

  // store W2 row (quad q = t>>2): coeffs at floats 12..23 (3 aligned b128)
  if ((t & 3) == 0) {
    float* row = LW + OW2 + (t >> 2) * 32;
    st4(row + 12, g0, g1, g2, g3);
    st4(row + 16, g4, g5, g6, g7);
    st4(row + 20, g8, g9, g10, g11);
  }
  // L3..L6 read only rows written by their own wave -> no barrier

  // ---------- L3: 32 merges x 8 lanes; DIN 11 -> DOUT 16; trips i0=0,4,8 ----------
  {
    const int m = t >> 3, r = t & 7;
    const float* A = LW + OW2 + (2 * m) * 32 + 12;
    const float* B = LW + OW2 + (2 * m + 1) * 32 + 12;
    float a0 = 0.f, a1 = 0.f, a2 = 0.f, a3 = 0.f;
    const int j0 = 4 * r;
    if (r < 5) {
#pragma unroll
      for (int i0 = 0; i0 <= 8; i0 += 4) {
        const float4 a4 = ld4(A + i0);
        const float4 bl = ld4(B + j0 - i0 - 4);
        const float4 bh = ld4(B + j0 - i0);
        CONV4(a4, bl, bh);
      }
      if (r == 4) { a1 = 0.f; a2 = 0.f; a3 = 0.f; }   // truncate deg>16
    }
    float mx = fmaxf(fmaxf(a0, a1), fmaxf(a2, a3));
    mx = fmaxf(mx, __shfl_xor(mx, 1));
    mx = fmaxf(mx, __shfl_xor(mx, 2));
    mx = fmaxf(mx, __shfl_xor(mx, 4));
    const float inv = 1.f / mx;
    if (r < 5) st4(LW + OW3 + m * 44 + 20 + j0, a0 * inv, a1 * inv, a2 * inv, a3 * inv);
    if (r == 0) scLog[m] = __logf(mx);
  }

  // ---------- L4: 16 merges x 16 lanes; DIN 16 -> DOUT 20; trips i0=0..16 ----------
  {
    const int m = t >> 4, r = t & 15;
    const float* A = LW + OW3 + (2 * m) * 44 + 20;
    const float* B = LW + OW3 + (2 * m + 1) * 44 + 20;
    float a0 = 0.f, a1 = 0.f, a2 = 0.f, a3 = 0.f;
    const int j0 = 4 * r;
    if (r < 6) {
#pragma unroll
      for (int i0 = 0; i0 <= 16; i0 += 4) {
        const float4 a4 = ld4(A + i0);
        const float4 bl = ld4(B + j0 - i0 - 4);
        const float4 bh = ld4(B + j0 - i0);
        CONV4(a4, bl, bh);
      }
      if (r == 5) { a1 = 0.f; a2 = 0.f; a3 = 0.f; }   // truncate deg>20
    }
    float mx = fmaxf(fmaxf(a0, a1), fmaxf(a2, a3));
    mx = fmaxf(mx, __shfl_xor(mx, 1));
    mx = fmaxf(mx, __shfl_xor(mx, 2));
    mx = fmaxf(mx, __shfl_xor(mx, 4));
    mx = fmaxf(mx, __shfl_xor(mx, 8));
    const float inv = 1.f / mx;
    if (r < 6) st4(LW + OW4 + m * 60 + 24 + j0, a0 * inv, a1 * inv, a2 * inv, a3 * inv);
    if (r == 0) scLog[32 + m] = __logf(mx);
  }

  // ---------- L5: 8 merges x 32 lanes; DIN 20 -> DOUT 32; trips i0=0..20 ----------
  {
    const int m = t >> 5, r = t & 31;
    const float* A = LW + OW4 + (2 * m) * 60 + 24;
    const float* B = LW + OW4 + (2 * m + 1) * 60 + 24;
    float a0 = 0.f, a1 = 0.f, a2 = 0.f, a3 = 0.f;
    const int j0 = 4 * r;
    if (r < 9) {
#pragma unroll
      for (int i0 = 0; i0 <= 20; i0 += 4) {
        const float4 a4 = ld4(A + i0);
        const float4 bl = ld4(B + j0 - i0 - 4);
        const float4 bh = ld4(B + j0 - i0);
        CONV4(a4, bl, bh);
      }
      if (r == 8) { a1 = 0.f; a2 = 0.f; a3 = 0.f; }   // truncate deg>32
    }
    float mx = fmaxf(fmaxf(a0, a1), fmaxf(a2, a3));
    mx = fmaxf(mx, __shfl_xor(mx, 1));
    mx = fmaxf(mx, __shfl_xor(mx, 2));
    mx = fmaxf(mx, __shfl_xor(mx, 4));
    mx = fmaxf(mx, __shfl_xor(mx, 8));
    mx = fmaxf(mx, __shfl_xor(mx, 16));
    const float inv = 1.f / mx;
    if (r < 9) st4(LW + OW5 + m * 84 + 36 + j0, a0 * inv, a1 * inv, a2 * inv, a3 * inv);
    if (r == 0) scLog[48 + m] = __logf(mx);
  }

  // ---------- L6: 4 merges x 64 lanes; DIN 32 -> DOUT 44; trips i0=0..32 ----------
  {
    const int r = t & 63;
    const float* A = LW + OW5 + (2 * wv) * 84 + 36;
    const float* B = LW + OW5 + (2 * wv + 1) * 84 + 36;
    float a0 = 0.f, a1 = 0.f, a2 = 0.f, a3 = 0.f;
    const int j0 = 4 * r;
    if (r < 12) {
#pragma unroll
      for (int i0 = 0; i0 <= 32; i0 += 4) {
        const float4 a4 = ld4(A + i0);
        const float4 bl = ld4(B + j0 - i0 - 4);
        const float4 bh = ld4(B + j0 - i0);
        CONV4(a4, bl, bh);
      }
      if (r == 11) { a1 = 0.f; a2 = 0.f; a3 = 0.f; }  // truncate deg>44
    }
    float mx = fmaxf(fmaxf(a0, a1), fmaxf(a2, a3));
#pragma unroll
    for (int msk = 1; msk < 64; msk <<= 1) mx = fmaxf(mx, __shfl_xor(mx, msk));
    const float inv = 1.f / mx;
    if (r < 12) st4(LW + OW6 + wv * 116 + 48 + j0, a0 * inv, a1 * inv, a2 * inv, a3 * inv);
    if (r == 0) scLog[56 + wv] = __logf(mx);
  }
  __syncthreads();                                   // barrier 2 (cross-wave W6)

  // ---------- L7: 2 merges x 32 lanes (wave 0); DIN 44 -> DOUT 64; i0=0..44 ----------
  if (t < 64) {
    const int m = (t >> 5) & 1, r = t & 31;
    const float* A = LW + OW6 + (2 * m) * 116 + 48;
    const float* B = LW + OW6 + (2 * m + 1) * 116 + 48;
    float a0 = 0.f, a1 = 0.f, a2 = 0.f, a3 = 0.f;
    const int j0 = 4 * r;
    if (r < 17) {
#pragma unroll
      for (int i0 = 0; i0 <= 44; i0 += 4) {
        const float4 a4 = ld4(A + i0);
        const float4 bl = ld4(B + j0 - i0 - 4);
        const float4 bh = ld4(B + j0 - i0);
        CONV4(a4, bl, bh);
      }
      if (r == 16) { a1 = 0.f; a2 = 0.f; a3 = 0.f; }  // keep only deg 64
    }
    float mx = fmaxf(fmaxf(a0, a1), fmaxf(a2, a3));
    mx = fmaxf(mx, __shfl_xor(mx, 1));
    mx = fmaxf(mx, __shfl_xor(mx, 2));
    mx = fmaxf(mx, __shfl_xor(mx, 4));
    mx = fmaxf(mx, __shfl_xor(mx, 8));
    mx = fmaxf(mx, __shfl_xor(mx, 16));
    const float inv = 1.f / mx;
    if (r < 17) st4(LW + OW7 + m * 68 + j0, a0 * inv, a1 * inv, a2 * inv, a3 * inv);
    if (r == 0) scLog[60 + m] = __logf(mx);
  }
  // L8 runs on wave 0 too -> same-wave LDS ordering, no barrier needed

  // ---------- L8: final degrees 63,64 + output ----------
  if (t < 64) {
    const float* A = LW + OW7;
    const float* B = LW + OW7 + 68;
    const float a = A[t];
    float v63 = a * B[63 - t];
    float v64 = a * B[64 - t];
    float ee = (t < 62) ? scLog[t] : 0.f;
#pragma unroll
    for (int msk = 1; msk < 64; msk <<= 1) {
      v63 += __shfl_xor(v63, msk);
      v64 += __shfl_xor(v64, msk);
      ee  += __shfl_xor(ee, msk);
    }
    if (t == 0) {
      v64 = fmaf(A[64], B[0], v64);
      const float Ssum = red[4] + red[5] + red[6] + red[7] + ee;
      out[s]      = __logf(v63) + Ssum + 63.f * tau;
      out[NS + s] = __logf(v64) + Ssum + 64.f * tau;
    }
  }
}

extern "C" void kernel_launch(void* const* d_in, const int* in_sizes, int n_in,
                              void* d_out, int out_size, void* d_ws, size_t ws_size,
                              hipStream_t stream) {
  const float* x = (const float*)d_in[0];
  float* out = (float*)d_out;
  (void)in_sizes; (void)n_in; (void)d_ws; (void)ws_size; (void)out_size;
  logesp_kernel<<<NS, 256, 0, stream>>>(x, out);
}